// Round 1
// baseline (646.837 us; speedup 1.0000x reference)
//
#include <hip/hip_runtime.h>
#include <stdint.h>

// LiquidStateMachine on MI355X.
// Key structure: batch rows are independent across all steps -> block owns
// R_PB=8 rows x all 512 neurons, runs all 64 steps with only intra-block
// barriers. W is ~10% sparse (masked entries exactly 0.0f) -> CSC sparse
// accumulate with binary spikes: exact fp32, ~3 VALU ops per (row,nnz).
//
// d_ws layout (built fresh every launch by two prep kernels; harness
// re-poisons d_ws before every timed call):
//   perm[512]  : sorted-rank -> actual column (ascending nnz count)
//   rank[512]  : actual column -> sorted rank
//   cnt[512]   : nnz per column
//   cntw[8]    : per wave-group (64 sorted cols) max nnz, padded to even
//   basew[8]   : per wave-group base slot (uint2 units) into entry stream
//   entries    : uint2 {k, bits(w)}, layout slot = base + (j>>1)*128 + lane*2 + (j&1)
//                so each lane reads its iters j,j+1 with ONE coalesced dwordx4.

#define N_NEU 512
#define B_ROWS 2048
#define D_IN 256
#define R_PB 8
#define NBLK (B_ROWS / R_PB)   // 256 blocks = 1 per CU

#define WS_PERM    0
#define WS_RANK    2048
#define WS_CNT     4096
#define WS_CNTW    6144
#define WS_BASE    6272
#define WS_ENTRIES 8192

// ---------------------------------------------------------------- prep 1
// Count nnz per column, sort columns by count (ascending), compute padded
// per-wave-group trip counts and entry-stream bases.
__global__ __launch_bounds__(1024) void lsm_count_sort(
    const float* __restrict__ W, uint32_t* __restrict__ ws)
{
    __shared__ int cnt2[2][N_NEU];
    __shared__ int cs[N_NEU];      // counts by column, then reused for group cw
    __shared__ int csort[N_NEU];   // counts by sorted rank

    int tid  = threadIdx.x;
    int col  = tid & (N_NEU - 1);
    int half = tid >> 9;           // 0 or 1: split k-range for ILP/parallelism
    int k0   = half * 256;
    int c = 0;
    #pragma unroll 4
    for (int k = 0; k < 256; ++k)
        c += (W[(size_t)(k0 + k) * N_NEU + col] != 0.0f) ? 1 : 0;
    cnt2[half][col] = c;
    __syncthreads();

    if (half == 0) {
        int cnt = cnt2[0][col] + cnt2[1][col];
        ws[(WS_CNT >> 2) + col] = (uint32_t)cnt;
        cs[col] = cnt;
    }
    __syncthreads();

    if (half == 0) {
        int cnt = cs[col];
        int rank = 0;
        for (int j = 0; j < N_NEU; ++j) {
            int cj = cs[j];
            rank += ((cj < cnt) || (cj == cnt && j < col)) ? 1 : 0;
        }
        ws[(WS_PERM >> 2) + rank] = (uint32_t)col;
        ws[(WS_RANK >> 2) + col]  = (uint32_t)rank;
        csort[rank] = cnt;
    }
    __syncthreads();

    if (tid < 8) {
        // ascending sort -> group max is last element of each 64-group
        int cw = csort[tid * 64 + 63];
        cw = (cw + 1) & ~1;        // pad to even (dwordx4 reads 2 entries)
        cs[tid] = cw;              // cs reuse: per-group padded count
        ws[(WS_CNTW >> 2) + tid] = (uint32_t)cw;
    }
    __syncthreads();

    if (tid == 0) {
        int acc = 0;
        for (int w = 0; w < 8; ++w) {
            ws[(WS_BASE >> 2) + w] = (uint32_t)acc;
            acc += cs[w] * 64;     // slots (uint2) per group
        }
    }
}

// ---------------------------------------------------------------- prep 2
// Scatter nonzeros of each column into its lane-interleaved slots; pad the
// tail with {k=0, w=0.0f} (harmless add of 0).
__global__ __launch_bounds__(64) void lsm_fill(
    const float* __restrict__ W, uint32_t* __restrict__ ws)
{
    int col  = blockIdx.x;
    int lane = threadIdx.x;
    uint32_t rank = ws[(WS_RANK >> 2) + col];
    int wg = (int)(rank >> 6);
    int ls = (int)(rank & 63);
    int cw = (int)ws[(WS_CNTW >> 2) + wg];
    uint32_t base = ws[(WS_BASE >> 2) + wg];
    uint2* entries = (uint2*)(ws + (WS_ENTRIES >> 2));

    __shared__ int ctr;
    if (lane == 0) ctr = 0;
    __syncthreads();

    for (int k = lane; k < N_NEU; k += 64) {
        float wv = W[(size_t)k * N_NEU + col];
        if (wv != 0.0f) {
            int j = atomicAdd(&ctr, 1);   // order within column is irrelevant
            uint32_t slot = base + (uint32_t)((j >> 1) * 128 + ls * 2 + (j & 1));
            entries[slot] = make_uint2((uint32_t)k, __float_as_uint(wv));
        }
    }
    __syncthreads();
    int cnt = ctr;
    for (int j = cnt + lane; j < cw; j += 64) {
        uint32_t slot = base + (uint32_t)((j >> 1) * 128 + ls * 2 + (j & 1));
        entries[slot] = make_uint2(0u, 0u);
    }
}

// ---------------------------------------------------------------- main
__global__ __launch_bounds__(512) void lsm_main(
    const float* __restrict__ rates, const float* __restrict__ inW,
    const float* __restrict__ vin,   const float* __restrict__ cin,
    const int* __restrict__ nsteps_p,
    const uint32_t* __restrict__ ws, float* __restrict__ out)
{
    __shared__ float rates_lds[R_PB][D_IN];       // 8 KB
    __shared__ unsigned char sbytes[N_NEU];       // spike bits, 8 rows/byte

    int p    = threadIdx.x;
    int blk  = blockIdx.x;
    int r0   = blk * R_PB;
    int wg   = p >> 6;
    int lane = p & 63;
    int n    = (int)ws[(WS_PERM >> 2) + p];       // actual column this thread owns
    int cw   = (int)ws[(WS_CNTW >> 2) + wg];      // uniform within wave
    uint32_t base = ws[(WS_BASE >> 2) + wg];
    const uint4* sp =
        (const uint4*)((const uint2*)(ws + (WS_ENTRIES >> 2)) + base) + lane;

    // stage this block's 8 rate rows (coalesced, 512 float4 / 512 threads)
    {
        const float4* src = (const float4*)(rates + (size_t)r0 * D_IN);
        float4* dst = (float4*)(&rates_lds[0][0]);
        dst[p] = src[p];
    }
    __syncthreads();

    // input current I[r] = rates[r,:] . inW[n,:]  (constant across steps)
    float I[R_PB];
    #pragma unroll
    for (int r = 0; r < R_PB; ++r) I[r] = 0.f;
    {
        const float4* wrow = (const float4*)(inW + (size_t)n * D_IN);
        for (int d4 = 0; d4 < D_IN / 4; ++d4) {
            float4 wv = wrow[d4];
            #pragma unroll
            for (int r = 0; r < R_PB; ++r) {
                I[r] += wv.x * rates_lds[r][d4 * 4 + 0]
                      + wv.y * rates_lds[r][d4 * 4 + 1]
                      + wv.z * rates_lds[r][d4 * 4 + 2]
                      + wv.w * rates_lds[r][d4 * 4 + 3];
            }
        }
    }

    // initial state + initial spike byte
    float c[R_PB], v[R_PB], ssum[R_PB];
    unsigned int byte0 = 0;
    #pragma unroll
    for (int r = 0; r < R_PB; ++r) {
        c[r] = cin[(size_t)(r0 + r) * N_NEU + n];
        v[r] = vin[(size_t)(r0 + r) * N_NEU + n];
        ssum[r] = 0.f;
        byte0 |= (c[r] > 0.f) ? (1u << r) : 0u;
    }
    sbytes[n] = (unsigned char)byte0;

    const float AS   = (float)0.8187307530779818;   // exp(-1/5)
    const float OMAS = (float)(1.0 - 0.8187307530779818);
    const float AM   = (float)0.9512294245007140;   // exp(-1/20)
    const float OMAM = (float)(1.0 - 0.9512294245007140);

    int T = nsteps_p[0];
    int halfc = cw >> 1;
    __syncthreads();

    for (int t = 0; t < T; ++t) {
        float rec[R_PB];
        #pragma unroll
        for (int r = 0; r < R_PB; ++r) rec[r] = 0.f;

        #pragma unroll 2
        for (int j2 = 0; j2 < halfc; ++j2) {
            uint4 e = sp[(size_t)j2 * 64];          // 2 entries, coalesced 16B/lane
            unsigned int b0 = sbytes[e.x];          // spike byte for k0
            unsigned int b1 = sbytes[e.z];          // spike byte for k1
            #pragma unroll
            for (int r = 0; r < R_PB; ++r) {
                int m0 = ((int)(b0 << (31 - r))) >> 31;   // 0 or -1 (v_bfe_i32)
                int m1 = ((int)(b1 << (31 - r))) >> 31;
                rec[r] += __int_as_float(e.y & (unsigned)m0)
                        + __int_as_float(e.w & (unsigned)m1);
            }
        }
        __syncthreads();   // everyone done reading sbytes

        unsigned int nb = 0;
        #pragma unroll
        for (int r = 0; r < R_PB; ++r) {
            c[r] = AS * c[r] + OMAS * (I[r] + rec[r]);
            v[r] = AM * v[r] + OMAM * c[r];
            ssum[r] += (v[r] > 0.f) ? 1.f : 0.f;
            nb |= (c[r] > 0.f) ? (1u << r) : 0u;
        }
        sbytes[n] = (unsigned char)nb;
        __syncthreads();   // new spikes visible
    }

    float invT = 1.0f / (float)T;     // T=64 -> exact
    size_t BN = (size_t)B_ROWS * N_NEU;
    #pragma unroll
    for (int r = 0; r < R_PB; ++r) {
        size_t off = (size_t)(r0 + r) * N_NEU + n;
        out[off]          = ssum[r] * invT;  // readout
        out[BN + off]     = v[r];            // final v
        out[2 * BN + off] = c[r];            // final c
    }
}

// ---------------------------------------------------------------- launch
extern "C" void kernel_launch(void* const* d_in, const int* in_sizes, int n_in,
                              void* d_out, int out_size, void* d_ws, size_t ws_size,
                              hipStream_t stream)
{
    const float* rates = (const float*)d_in[0];
    const float* inW   = (const float*)d_in[1];
    const float* W     = (const float*)d_in[2];
    const float* vin   = (const float*)d_in[3];
    const float* cin   = (const float*)d_in[4];
    const int*   nst   = (const int*)d_in[5];
    uint32_t* ws = (uint32_t*)d_ws;
    float* out = (float*)d_out;
    (void)in_sizes; (void)n_in; (void)out_size; (void)ws_size;

    lsm_count_sort<<<1, 1024, 0, stream>>>(W, ws);
    lsm_fill<<<N_NEU, 64, 0, stream>>>(W, ws);
    lsm_main<<<NBLK, 512, 0, stream>>>(rates, inW, vin, cin, nst, ws, out);
}

// Round 3
// 616.394 us; speedup vs baseline: 1.0494x; 1.0494x over previous
//
#include <hip/hip_runtime.h>
#include <stdint.h>

// LiquidStateMachine on MI355X — round 3.
// Round-2 failure root cause: packing k into the low 9 mantissa bits of w
// (rel err 2^-14) flipped spikes through the recurrent threshold dynamics
// (absmax 0.03 -> 0.31). Fix: EXACT fp32 weights, separate ushort index
// stream (6 B/entry total, vs 8 B for {k,w} pairs) to keep L2 re-read
// bandwidth at ~21 TB/s < 34.5 TB/s ceiling.
//
// Structure: block owns R_PB=4 batch rows x all 512 neurons, all 64 steps
// intra-block (batch rows independent -> no grid sync). W ~10% sparse ->
// per-column entry streams, columns counting-sorted by nnz so each wave's
// 64 lanes have near-equal trips; streams lane-interleaved so one dwordx4
// covers 8 entries (indices) / 4 entries (weights). Spike bits (4 rows per
// byte) at LDS offset 0 so ds_read_u8 address == k.
//
// d_ws layout (bytes):
//   0      PERM[512]  sorted-rank -> column
//   2048   RANK[512]  column -> sorted rank
//   4096   CNT[512]   nnz per column          (zeroed via hipMemsetAsync)
//   6144   CTR[512]   fill cursors            (zeroed via hipMemsetAsync)
//   8192   CNTW[8]    per-group padded trip count (multiple of 8)
//   8256   IBASE[8]   per-group byte base into IDX region
//   8320   WBASE[8]   per-group byte base into WT region
//   16384  IDX        ushort ks: byte = ib + (j>>3)*1024 + ls*16 + (j&7)*2
//   98304  WT         fp32 ws:   byte = wb + (j>>3)*2048 + ls*32 + (j&7)*4

#define N_NEU 512
#define B_ROWS 2048
#define D_IN 256
#define R_PB 4
#define NBLK (B_ROWS / R_PB)   // 512 blocks = 2 per CU

#define WS_PERM    0
#define WS_RANK    2048
#define WS_CNT     4096
#define WS_CTR     6144
#define WS_CNTW    8192
#define WS_IBASE   8256
#define WS_WBASE   8320
#define WS_IDX     16384
#define WS_WT      98304

#if defined(__has_builtin)
#if __has_builtin(__builtin_amdgcn_sbfe)
#define SBFE(b, r) __builtin_amdgcn_sbfe((int)(b), (unsigned)(r), 1u)
#endif
#endif
#ifndef SBFE
#define SBFE(b, r) (((int)((unsigned)(b) << (31 - (r)))) >> 31)
#endif

// ---------------------------------------------------------------- prep A
// Count nnz per column. 128 blocks x 256 threads; block b covers k rows
// [4b,4b+4), thread t covers columns {t, t+256}. Coalesced row reads.
__global__ __launch_bounds__(256) void lsm_count(
    const float* __restrict__ W, uint32_t* __restrict__ ws)
{
    int t  = threadIdx.x;
    int k0 = blockIdx.x * 4;
    int c0 = 0, c1 = 0;
    #pragma unroll
    for (int kk = 0; kk < 4; ++kk) {
        const float* row = W + (size_t)(k0 + kk) * N_NEU;
        c0 += (row[t]       != 0.0f) ? 1 : 0;
        c1 += (row[t + 256] != 0.0f) ? 1 : 0;
    }
    if (c0) atomicAdd(&ws[(WS_CNT >> 2) + t],       (uint32_t)c0);
    if (c1) atomicAdd(&ws[(WS_CNT >> 2) + t + 256], (uint32_t)c1);
}

// ---------------------------------------------------------------- prep B
// Counting-sort columns ascending by nnz (full-range hist so group max is
// exact); per-group padded trip counts + stream bases; write pad entries
// (k=0, w=+0.0f -> harmless add of 0).
__global__ __launch_bounds__(512) void lsm_sort(uint32_t* __restrict__ ws)
{
    __shared__ int hist[N_NEU + 1];
    __shared__ int csort[N_NEU];
    __shared__ int gcw[8];

    int t = threadIdx.x;
    int creal = (int)ws[(WS_CNT >> 2) + t];
    for (int i = t; i < N_NEU + 1; i += 512) hist[i] = 0;
    __syncthreads();
    atomicAdd(&hist[creal], 1);
    __syncthreads();
    if (t == 0) {
        int acc = 0;
        for (int v = 0; v <= N_NEU; ++v) { int h = hist[v]; hist[v] = acc; acc += h; }
    }
    __syncthreads();
    int rank = atomicAdd(&hist[creal], 1);   // ties in arbitrary order (fine)
    ws[(WS_PERM >> 2) + rank] = (uint32_t)t;
    ws[(WS_RANK >> 2) + t]    = (uint32_t)rank;
    csort[rank] = creal;
    __syncthreads();
    if (t < 8) {
        int cw = csort[t * 64 + 63];         // ascending -> group max is last
        cw = (cw + 7) & ~7;                  // pad to multiple of 8
        gcw[t] = cw;
        ws[(WS_CNTW >> 2) + t] = (uint32_t)cw;
    }
    __syncthreads();
    if (t == 0) {
        int ai = 0, aw = 0;
        for (int g = 0; g < 8; ++g) {
            ws[(WS_IBASE >> 2) + g] = (uint32_t)ai;
            ws[(WS_WBASE >> 2) + g] = (uint32_t)aw;
            ai += gcw[g] * 64 * 2;           // bytes
            aw += gcw[g] * 64 * 4;           // bytes
        }
    }
    __syncthreads();
    // pad tail slots of this thread's column
    int wg = rank >> 6, ls = rank & 63;
    int cw = gcw[wg];
    uint32_t ib = ws[(WS_IBASE >> 2) + wg];
    uint32_t wb = ws[(WS_WBASE >> 2) + wg];
    char* base = (char*)ws;
    for (int j = creal; j < cw; ++j) {
        *(unsigned short*)(base + WS_IDX + ib + (j >> 3) * 1024 + ls * 16 + (j & 7) * 2) = 0;
        *(float*)(base + WS_WT + wb + (j >> 3) * 2048 + ls * 32 + (j & 7) * 4) = 0.0f;
    }
}

// ---------------------------------------------------------------- prep C
// Scatter nonzeros: 512 blocks (one per k row), coalesced row reads, atomic
// cursor per column. Byte/short stores to distinct bytes -> no races.
__global__ __launch_bounds__(64) void lsm_fill(
    const float* __restrict__ W, uint32_t* __restrict__ ws)
{
    int k    = blockIdx.x;
    int lane = threadIdx.x;
    char* base = (char*)ws;
    const float* row = W + (size_t)k * N_NEU;
    for (int c = lane; c < N_NEU; c += 64) {
        float wv = row[c];
        if (wv != 0.0f) {
            uint32_t rank = ws[(WS_RANK >> 2) + c];
            int wg = (int)(rank >> 6), ls = (int)(rank & 63);
            int j = (int)atomicAdd(&ws[(WS_CTR >> 2) + c], 1u);
            uint32_t ib = ws[(WS_IBASE >> 2) + wg];
            uint32_t wb = ws[(WS_WBASE >> 2) + wg];
            *(unsigned short*)(base + WS_IDX + ib + (j >> 3) * 1024 + ls * 16 + (j & 7) * 2)
                = (unsigned short)k;
            *(float*)(base + WS_WT + wb + (j >> 3) * 2048 + ls * 32 + (j & 7) * 4) = wv;
        }
    }
}

// ---------------------------------------------------------------- main
__global__ __launch_bounds__(512, 4) void lsm_main(
    const float* __restrict__ rates, const float* __restrict__ inW,
    const float* __restrict__ vin,   const float* __restrict__ cin,
    const int* __restrict__ nsteps_p,
    const uint32_t* __restrict__ ws, float* __restrict__ out)
{
    // sbytes MUST be at LDS offset 0: ds_read_u8 address == k, no add.
    __shared__ __align__(16) unsigned char smem[N_NEU + R_PB * D_IN * 4];
    unsigned char* sbytes = smem;                    // [512] spike bits
    float* rl = (float*)(smem + N_NEU);              // [R_PB][256] rates

    int p    = threadIdx.x;
    int blk  = blockIdx.x;
    int r0   = blk * R_PB;
    int wg   = p >> 6;
    int lane = p & 63;
    int n    = (int)ws[(WS_PERM >> 2) + p];
    int cw   = (int)ws[(WS_CNTW >> 2) + wg];         // wave-uniform
    int nit  = cw >> 3;                              // iterations of 8 entries
    const char* ip0 = (const char*)ws + WS_IDX + ws[(WS_IBASE >> 2) + wg] + lane * 16;
    const char* wp0 = (const char*)ws + WS_WT  + ws[(WS_WBASE >> 2) + wg] + lane * 32;

    // stage this block's 4 rate rows (1024 floats = 256 float4)
    if (p < 256)
        ((float4*)rl)[p] = ((const float4*)(rates + (size_t)r0 * D_IN))[p];
    __syncthreads();

    // input current I[r] = rates[r,:] . inW[n,:]  (constant across steps)
    float I[R_PB] = {0.f, 0.f, 0.f, 0.f};
    {
        const float4* wrow = (const float4*)(inW + (size_t)n * D_IN);
        for (int d4 = 0; d4 < D_IN / 4; ++d4) {
            float4 wv = wrow[d4];
            #pragma unroll
            for (int r = 0; r < R_PB; ++r) {
                const float* rr = rl + r * D_IN + d4 * 4;   // LDS broadcast
                I[r] += wv.x * rr[0] + wv.y * rr[1] + wv.z * rr[2] + wv.w * rr[3];
            }
        }
    }

    float c[R_PB], v[R_PB], ssum[R_PB];
    unsigned int byte0 = 0;
    #pragma unroll
    for (int r = 0; r < R_PB; ++r) {
        c[r] = cin[(size_t)(r0 + r) * N_NEU + n];
        v[r] = vin[(size_t)(r0 + r) * N_NEU + n];
        ssum[r] = 0.f;
        byte0 |= (c[r] > 0.f) ? (1u << r) : 0u;
    }
    sbytes[n] = (unsigned char)byte0;

    const float AS   = (float)0.8187307530779818;   // exp(-1/5)
    const float OMAS = (float)(1.0 - 0.8187307530779818);
    const float AM   = (float)0.9512294245007140;   // exp(-1/20)
    const float OMAM = (float)(1.0 - 0.9512294245007140);

    int T = nsteps_p[0];
    __syncthreads();

    for (int t = 0; t < T; ++t) {
        float rec0 = 0.f, rec1 = 0.f, rec2 = 0.f, rec3 = 0.f;

        const char* ipc = ip0;
        const char* wpc = wp0;
        uint4  cI  = *(const uint4*)ipc;
        float4 cWa = ((const float4*)wpc)[0];
        float4 cWb = ((const float4*)wpc)[1];
        unsigned kk[8], pb[8];
        kk[0] = cI.x & 0xffffu; kk[1] = cI.x >> 16;
        kk[2] = cI.y & 0xffffu; kk[3] = cI.y >> 16;
        kk[4] = cI.z & 0xffffu; kk[5] = cI.z >> 16;
        kk[6] = cI.w & 0xffffu; kk[7] = cI.w >> 16;
        #pragma unroll
        for (int j = 0; j < 8; ++j) pb[j] = sbytes[kk[j]];

        for (int it = 0; it < nit - 1; ++it) {
            ipc += 1024; wpc += 2048;
            uint4  nI  = *(const uint4*)ipc;         // prefetch next 8 entries
            float4 nWa = ((const float4*)wpc)[0];
            float4 nWb = ((const float4*)wpc)[1];

            float wv[8] = {cWa.x, cWa.y, cWa.z, cWa.w, cWb.x, cWb.y, cWb.z, cWb.w};
            #pragma unroll
            for (int j = 0; j < 8; ++j) {
                unsigned wb = __float_as_uint(wv[j]);
                unsigned b  = pb[j];
                rec0 += __int_as_float(wb & (unsigned)SBFE(b, 0));
                rec1 += __int_as_float(wb & (unsigned)SBFE(b, 1));
                rec2 += __int_as_float(wb & (unsigned)SBFE(b, 2));
                rec3 += __int_as_float(wb & (unsigned)SBFE(b, 3));
            }
            kk[0] = nI.x & 0xffffu; kk[1] = nI.x >> 16;
            kk[2] = nI.y & 0xffffu; kk[3] = nI.y >> 16;
            kk[4] = nI.z & 0xffffu; kk[5] = nI.z >> 16;
            kk[6] = nI.w & 0xffffu; kk[7] = nI.w >> 16;
            #pragma unroll
            for (int j = 0; j < 8; ++j) pb[j] = sbytes[kk[j]];
            cWa = nWa; cWb = nWb;
        }
        {   // final iteration (no prefetch)
            float wv[8] = {cWa.x, cWa.y, cWa.z, cWa.w, cWb.x, cWb.y, cWb.z, cWb.w};
            #pragma unroll
            for (int j = 0; j < 8; ++j) {
                unsigned wb = __float_as_uint(wv[j]);
                unsigned b  = pb[j];
                rec0 += __int_as_float(wb & (unsigned)SBFE(b, 0));
                rec1 += __int_as_float(wb & (unsigned)SBFE(b, 1));
                rec2 += __int_as_float(wb & (unsigned)SBFE(b, 2));
                rec3 += __int_as_float(wb & (unsigned)SBFE(b, 3));
            }
        }
        __syncthreads();   // all spike-byte reads done

        float rec[R_PB] = {rec0, rec1, rec2, rec3};
        unsigned int nb = 0;
        #pragma unroll
        for (int r = 0; r < R_PB; ++r) {
            c[r] = AS * c[r] + OMAS * (I[r] + rec[r]);
            v[r] = AM * v[r] + OMAM * c[r];
            ssum[r] += (v[r] > 0.f) ? 1.f : 0.f;
            nb |= (c[r] > 0.f) ? (1u << r) : 0u;
        }
        sbytes[n] = (unsigned char)nb;
        __syncthreads();   // new spikes visible
    }

    float invT = 1.0f / (float)T;
    size_t BN = (size_t)B_ROWS * N_NEU;
    #pragma unroll
    for (int r = 0; r < R_PB; ++r) {
        size_t off = (size_t)(r0 + r) * N_NEU + n;
        out[off]          = ssum[r] * invT;  // readout
        out[BN + off]     = v[r];            // final v
        out[2 * BN + off] = c[r];            // final c
    }
}

// ---------------------------------------------------------------- launch
extern "C" void kernel_launch(void* const* d_in, const int* in_sizes, int n_in,
                              void* d_out, int out_size, void* d_ws, size_t ws_size,
                              hipStream_t stream)
{
    const float* rates = (const float*)d_in[0];
    const float* inW   = (const float*)d_in[1];
    const float* W     = (const float*)d_in[2];
    const float* vin   = (const float*)d_in[3];
    const float* cin   = (const float*)d_in[4];
    const int*   nst   = (const int*)d_in[5];
    uint32_t* ws = (uint32_t*)d_ws;
    float* out = (float*)d_out;
    (void)in_sizes; (void)n_in; (void)out_size; (void)ws_size;

    // zero CNT + CTR (harness poisons d_ws to 0xAA before every call)
    hipMemsetAsync((char*)d_ws + WS_CNT, 0, 4096, stream);

    lsm_count<<<128, 256, 0, stream>>>(W, ws);
    lsm_sort<<<1, 512, 0, stream>>>(ws);
    lsm_fill<<<N_NEU, 64, 0, stream>>>(W, ws);
    lsm_main<<<NBLK, 512, 0, stream>>>(rates, inW, vin, cin, nst, ws, out);
}

// Round 4
// 583.710 us; speedup vs baseline: 1.1081x; 1.0560x over previous
//
#include <hip/hip_runtime.h>
#include <stdint.h>

// LiquidStateMachine on MI355X — round 4.
// r3 analysis: at 4 waves/SIMD the kernel sat at ~568us with neither the
// VALU (~230us real, if the gfx94x VALUBusy formula 2x-inflates on gfx950)
// nor the LDS gather pipe (~232us) saturated -> latency-stall bound.
// Fix: 8 waves/SIMD at IDENTICAL per-CU work: 512 blocks x 1024 threads,
// each block = two 512-thread halves splitting every column's entry stream
// by alternating 8-entry groups; partial recs merge via LDS each step.
// VGPR <= 64 required for 2 blocks/CU: __launch_bounds__(1024,8), I and
// ssum parked in LDS across the loop, no manual pipeline (unroll 1).
// Weights stay EXACT fp32 (r2 lesson: any weight rounding flips spikes
// through the recurrent threshold); ushort index stream + fp32 weight
// stream = 6 B/entry.
//
// d_ws layout (bytes):
//   0      PERM[512]  sorted-rank -> column
//   2048   RANK[512]  column -> sorted rank
//   4096   CNT[512]   nnz per column          (zeroed via hipMemsetAsync)
//   6144   CTR[512]   (unused this round)
//   8192   CNTW[8]    per-group padded trip count (multiple of 16)
//   8256   IBASE[8]   per-group byte base into IDX region
//   8320   WBASE[8]   per-group byte base into WT region
//   16384  IDX        ushort ks: byte = ib + (j>>3)*1024 + ls*16 + (j&7)*2
//   98304  WT         fp32 ws:   byte = wb + (j>>3)*2048 + ls*32 + (j&7)*4

#define N_NEU 512
#define B_ROWS 2048
#define D_IN 256
#define R_PB 4
#define NBLK (B_ROWS / R_PB)   // 512 blocks, 1024 threads -> 2 blocks/CU, 32 waves/CU

#define WS_PERM    0
#define WS_RANK    2048
#define WS_CNT     4096
#define WS_CTR     6144
#define WS_CNTW    8192
#define WS_IBASE   8256
#define WS_WBASE   8320
#define WS_IDX     16384
#define WS_WT      98304

#if defined(__has_builtin)
#if __has_builtin(__builtin_amdgcn_sbfe)
#define SBFE(b, r) __builtin_amdgcn_sbfe((int)(b), (unsigned)(r), 1u)
#endif
#endif
#ifndef SBFE
#define SBFE(b, r) (((int)((unsigned)(b) << (31 - (r)))) >> 31)
#endif

// ---------------------------------------------------------------- prep A
__global__ __launch_bounds__(256) void lsm_count(
    const float* __restrict__ W, uint32_t* __restrict__ ws)
{
    int t  = threadIdx.x;
    int k0 = blockIdx.x * 4;
    int c0 = 0, c1 = 0;
    #pragma unroll
    for (int kk = 0; kk < 4; ++kk) {
        const float* row = W + (size_t)(k0 + kk) * N_NEU;
        c0 += (row[t]       != 0.0f) ? 1 : 0;
        c1 += (row[t + 256] != 0.0f) ? 1 : 0;
    }
    if (c0) atomicAdd(&ws[(WS_CNT >> 2) + t],       (uint32_t)c0);
    if (c1) atomicAdd(&ws[(WS_CNT >> 2) + t + 256], (uint32_t)c1);
}

// ---------------------------------------------------------------- prep B
// Counting-sort columns ascending by nnz; per-group padded trip counts
// (multiple of 16 so both halves get whole 8-entry groups) + bases; pad
// entries (k=0, w=+0.0f -> harmless add of 0).
__global__ __launch_bounds__(512) void lsm_sort(uint32_t* __restrict__ ws)
{
    __shared__ int hist[N_NEU + 1];
    __shared__ int csort[N_NEU];
    __shared__ int gcw[8];

    int t = threadIdx.x;
    int creal = (int)ws[(WS_CNT >> 2) + t];
    for (int i = t; i < N_NEU + 1; i += 512) hist[i] = 0;
    __syncthreads();
    atomicAdd(&hist[creal], 1);
    __syncthreads();
    if (t == 0) {
        int acc = 0;
        for (int v = 0; v <= N_NEU; ++v) { int h = hist[v]; hist[v] = acc; acc += h; }
    }
    __syncthreads();
    int rank = atomicAdd(&hist[creal], 1);
    ws[(WS_PERM >> 2) + rank] = (uint32_t)t;
    ws[(WS_RANK >> 2) + t]    = (uint32_t)rank;
    csort[rank] = creal;
    __syncthreads();
    if (t < 8) {
        int cw = csort[t * 64 + 63];         // ascending -> group max is last
        cw = (cw + 15) & ~15;                // pad to multiple of 16
        gcw[t] = cw;
        ws[(WS_CNTW >> 2) + t] = (uint32_t)cw;
    }
    __syncthreads();
    if (t == 0) {
        int ai = 0, aw = 0;
        for (int g = 0; g < 8; ++g) {
            ws[(WS_IBASE >> 2) + g] = (uint32_t)ai;
            ws[(WS_WBASE >> 2) + g] = (uint32_t)aw;
            ai += gcw[g] * 64 * 2;           // bytes
            aw += gcw[g] * 64 * 4;           // bytes
        }
    }
    __syncthreads();
    // pad tail slots of this thread's column
    int wg = rank >> 6, ls = rank & 63;
    int cw = gcw[wg];
    uint32_t ib = ws[(WS_IBASE >> 2) + wg];
    uint32_t wb = ws[(WS_WBASE >> 2) + wg];
    char* base = (char*)ws;
    for (int j = creal; j < cw; ++j) {
        *(unsigned short*)(base + WS_IDX + ib + (j >> 3) * 1024 + ls * 16 + (j & 7) * 2) = 0;
        *(float*)(base + WS_WT + wb + (j >> 3) * 2048 + ls * 32 + (j & 7) * 4) = 0.0f;
    }
}

// ---------------------------------------------------------------- prep C
// One block per COLUMN, LDS-local cursor (no global atomic contention).
__global__ __launch_bounds__(64) void lsm_fill(
    const float* __restrict__ W, uint32_t* __restrict__ ws)
{
    int c    = blockIdx.x;
    int lane = threadIdx.x;
    char* base = (char*)ws;
    uint32_t rank = ws[(WS_RANK >> 2) + c];
    int wg = (int)(rank >> 6), ls = (int)(rank & 63);
    uint32_t ib = ws[(WS_IBASE >> 2) + wg];
    uint32_t wb = ws[(WS_WBASE >> 2) + wg];

    __shared__ int ctr;
    if (lane == 0) ctr = 0;
    __syncthreads();

    for (int k = lane; k < N_NEU; k += 64) {
        float wv = W[(size_t)k * N_NEU + c];
        if (wv != 0.0f) {
            int j = atomicAdd(&ctr, 1);      // order within column irrelevant
            *(unsigned short*)(base + WS_IDX + ib + (j >> 3) * 1024 + ls * 16 + (j & 7) * 2)
                = (unsigned short)k;
            *(float*)(base + WS_WT + wb + (j >> 3) * 2048 + ls * 32 + (j & 7) * 4) = wv;
        }
    }
}

// ---------------------------------------------------------------- main
// LDS map (sbytes MUST be at offset 0: ds_read_u8 addr == k):
//   [0,512)        sbytes: spike bits, 4 rows/byte
//   [512,8704)     Ibuf  : float4 per column  (input current, 4 rows)
//   [8704,16896)   SSbuf : float4 per column  (spike-count accum, 4 rows)
//   [16896,25088)  recx  : float4 per column  (half-1 partial rec)
//                  rl    : overlays recx (rates staging, used pre-loop only)
__global__ __launch_bounds__(1024, 8) void lsm_main(
    const float* __restrict__ rates, const float* __restrict__ inW,
    const float* __restrict__ vin,   const float* __restrict__ cin,
    const int* __restrict__ nsteps_p,
    const uint32_t* __restrict__ ws, float* __restrict__ out)
{
    __shared__ __align__(16) unsigned char smem[25088];
    unsigned char* sbytes = smem;
    float4* Ibuf  = (float4*)(smem + 512);
    float4* SSbuf = (float4*)(smem + 8704);
    float4* recx  = (float4*)(smem + 16896);
    float*  rl    = (float*)(smem + 16896);      // overlay, pre-loop only

    int p    = threadIdx.x;
    int h    = p >> 9;          // half: 0 or 1
    int q    = p & 511;         // column slot
    int blk  = blockIdx.x;
    int r0   = blk * R_PB;
    int wg   = q >> 6;
    int lane = q & 63;
    int n    = (int)ws[(WS_PERM >> 2) + q];
    int cw   = (int)ws[(WS_CNTW >> 2) + wg];     // wave-uniform
    int nit  = cw >> 4;                          // 8-entry groups per half
    const char* ip0 = (const char*)ws + WS_IDX + ws[(WS_IBASE >> 2) + wg]
                    + h * 1024 + lane * 16;
    const char* wp0 = (const char*)ws + WS_WT  + ws[(WS_WBASE >> 2) + wg]
                    + h * 2048 + lane * 32;

    // stage this block's 4 rate rows into rl (256 float4 loads)
    if (p < 256)
        ((float4*)rl)[p] = ((const float4*)(rates + (size_t)r0 * D_IN))[p];
    __syncthreads();

    // half 0: input current I[r] = rates[r,:].inW[n,:]; park in LDS.
    // half 0: load state, init spike byte + ssum.
    float c0v[R_PB], v0v[R_PB];
    if (h == 0) {
        float I[R_PB] = {0.f, 0.f, 0.f, 0.f};
        const float4* wrow = (const float4*)(inW + (size_t)n * D_IN);
        for (int d4 = 0; d4 < D_IN / 4; ++d4) {
            float4 wv = wrow[d4];
            #pragma unroll
            for (int r = 0; r < R_PB; ++r) {
                const float* rr = rl + r * D_IN + d4 * 4;   // LDS broadcast
                I[r] += wv.x * rr[0] + wv.y * rr[1] + wv.z * rr[2] + wv.w * rr[3];
            }
        }
        unsigned int byte0 = 0;
        #pragma unroll
        for (int r = 0; r < R_PB; ++r) {
            c0v[r] = cin[(size_t)(r0 + r) * N_NEU + n];
            v0v[r] = vin[(size_t)(r0 + r) * N_NEU + n];
            byte0 |= (c0v[r] > 0.f) ? (1u << r) : 0u;
        }
        __syncthreads();   // everyone done with rl before Ibuf/recx writes
        Ibuf[q]  = make_float4(I[0], I[1], I[2], I[3]);
        SSbuf[q] = make_float4(0.f, 0.f, 0.f, 0.f);
        sbytes[n] = (unsigned char)byte0;
    } else {
        __syncthreads();   // matching barrier
    }

    const float AS   = (float)0.8187307530779818;   // exp(-1/5)
    const float OMAS = (float)(1.0 - 0.8187307530779818);
    const float AM   = (float)0.9512294245007140;   // exp(-1/20)
    const float OMAM = (float)(1.0 - 0.9512294245007140);

    int T = nsteps_p[0];
    __syncthreads();

    #pragma unroll 1
    for (int t = 0; t < T; ++t) {
        float rec0 = 0.f, rec1 = 0.f, rec2 = 0.f, rec3 = 0.f;
        const char* ip = ip0;
        const char* wp = wp0;

        #pragma unroll 1
        for (int it = 0; it < nit; ++it) {
            uint4  I4 = *(const uint4*)ip;
            float4 Wa = ((const float4*)wp)[0];
            float4 Wb = ((const float4*)wp)[1];
            ip += 2048; wp += 4096;
            unsigned b0 = sbytes[I4.x & 0xffffu];
            unsigned b1 = sbytes[I4.x >> 16];
            unsigned b2 = sbytes[I4.y & 0xffffu];
            unsigned b3 = sbytes[I4.y >> 16];
            unsigned b4 = sbytes[I4.z & 0xffffu];
            unsigned b5 = sbytes[I4.z >> 16];
            unsigned b6 = sbytes[I4.w & 0xffffu];
            unsigned b7 = sbytes[I4.w >> 16];
#define ACC(WW, BB) { unsigned wbits = __float_as_uint(WW); \
            rec0 += __int_as_float(wbits & (unsigned)SBFE(BB, 0)); \
            rec1 += __int_as_float(wbits & (unsigned)SBFE(BB, 1)); \
            rec2 += __int_as_float(wbits & (unsigned)SBFE(BB, 2)); \
            rec3 += __int_as_float(wbits & (unsigned)SBFE(BB, 3)); }
            ACC(Wa.x, b0) ACC(Wa.y, b1) ACC(Wa.z, b2) ACC(Wa.w, b3)
            ACC(Wb.x, b4) ACC(Wb.y, b5) ACC(Wb.z, b6) ACC(Wb.w, b7)
#undef ACC
        }

        if (h == 1)
            recx[q] = make_float4(rec0, rec1, rec2, rec3);
        __syncthreads();   // half-1 partials visible; all sbytes reads done

        if (h == 0) {
            float4 rx = recx[q];
            float4 Iv = Ibuf[q];
            float4 ss = SSbuf[q];
            float rec[R_PB] = {rec0 + rx.x, rec1 + rx.y, rec2 + rx.z, rec3 + rx.w};
            float Ia[R_PB]  = {Iv.x, Iv.y, Iv.z, Iv.w};
            float ssa[R_PB] = {ss.x, ss.y, ss.z, ss.w};
            unsigned int nb = 0;
            #pragma unroll
            for (int r = 0; r < R_PB; ++r) {
                c0v[r] = AS * c0v[r] + OMAS * (Ia[r] + rec[r]);
                v0v[r] = AM * v0v[r] + OMAM * c0v[r];
                ssa[r] += (v0v[r] > 0.f) ? 1.f : 0.f;
                nb |= (c0v[r] > 0.f) ? (1u << r) : 0u;
            }
            SSbuf[q] = make_float4(ssa[0], ssa[1], ssa[2], ssa[3]);
            sbytes[n] = (unsigned char)nb;
        }
        __syncthreads();   // new spikes + ssum visible
    }

    if (h == 0) {
        float4 ss = SSbuf[q];
        float ssa[R_PB] = {ss.x, ss.y, ss.z, ss.w};
        float invT = 1.0f / (float)T;
        size_t BN = (size_t)B_ROWS * N_NEU;
        #pragma unroll
        for (int r = 0; r < R_PB; ++r) {
            size_t off = (size_t)(r0 + r) * N_NEU + n;
            out[off]          = ssa[r] * invT;   // readout
            out[BN + off]     = v0v[r];          // final v
            out[2 * BN + off] = c0v[r];          // final c
        }
    }
}

// ---------------------------------------------------------------- launch
extern "C" void kernel_launch(void* const* d_in, const int* in_sizes, int n_in,
                              void* d_out, int out_size, void* d_ws, size_t ws_size,
                              hipStream_t stream)
{
    const float* rates = (const float*)d_in[0];
    const float* inW   = (const float*)d_in[1];
    const float* W     = (const float*)d_in[2];
    const float* vin   = (const float*)d_in[3];
    const float* cin   = (const float*)d_in[4];
    const int*   nst   = (const int*)d_in[5];
    uint32_t* ws = (uint32_t*)d_ws;
    float* out = (float*)d_out;
    (void)in_sizes; (void)n_in; (void)out_size; (void)ws_size;

    // zero CNT (harness poisons d_ws to 0xAA before every call)
    hipMemsetAsync((char*)d_ws + WS_CNT, 0, 4096, stream);

    lsm_count<<<128, 256, 0, stream>>>(W, ws);
    lsm_sort<<<1, 512, 0, stream>>>(ws);
    lsm_fill<<<N_NEU, 64, 0, stream>>>(W, ws);
    lsm_main<<<NBLK, 1024, 0, stream>>>(rates, inW, vin, cin, nst, ws, out);
}

// Round 5
// 416.143 us; speedup vs baseline: 1.5544x; 1.4027x over previous
//
#include <hip/hip_runtime.h>
#include <stdint.h>

// LiquidStateMachine on MI355X — round 5.
// r4 lesson: VALU-issue bound (VALUBusy 83% at both 4 and 8 waves/SIMD;
// occupancy 24->75% changed nothing). Fix: kill the bit-unpack arithmetic.
// Spikes stored as f16 0.0/1.0 per (neuron,row) in LDS; inner loop per
// entry = 1 ds_read_b128 (8 rows' spikes, addr = pre-scaled k*16 straight
// from the index stream) + 8 fma(w,(float)spike,acc) -> 1-2 VALU per
// row-entry vs 3.6 before. R_PB=8 halves per-CU entries (VALU and LDS).
// Weights remain EXACT fp32 (r2: any weight rounding flips spikes);
// f16 spike 0/1 is exact, so only summation order differs from reference.
//
// d_ws layout (bytes):
//   0      PERM[512]  sorted-rank -> column
//   2048   RANK[512]  column -> sorted rank
//   4096   CNT[512]   nnz per column          (zeroed via hipMemsetAsync)
//   8192   CNTW[8]    per-group padded trip count (multiple of 16)
//   8256   IBASE[8]   per-group byte base into IDX region
//   8320   WBASE[8]   per-group byte base into WT region
//   16384  IDX        u16 (k*16): byte = ib + (j>>3)*1024 + ls*16 + (j&7)*2
//   81920  WT         f32 w:      byte = wb + (j>>3)*2048 + ls*32 + (j&7)*4

#define N_NEU 512
#define B_ROWS 2048
#define D_IN 256
#define R_PB 8
#define NBLK (B_ROWS / R_PB)   // 256 blocks x 1024 threads = 1 block/CU

#define WS_PERM    0
#define WS_RANK    2048
#define WS_CNT     4096
#define WS_CNTW    8192
#define WS_IBASE   8256
#define WS_WBASE   8320
#define WS_IDX     16384
#define WS_WT      81920

typedef _Float16 half8 __attribute__((ext_vector_type(8)));

// ---------------------------------------------------------------- prep A
__global__ __launch_bounds__(256) void lsm_count(
    const float* __restrict__ W, uint32_t* __restrict__ ws)
{
    int t  = threadIdx.x;
    int k0 = blockIdx.x * 4;
    int c0 = 0, c1 = 0;
    #pragma unroll
    for (int kk = 0; kk < 4; ++kk) {
        const float* row = W + (size_t)(k0 + kk) * N_NEU;
        c0 += (row[t]       != 0.0f) ? 1 : 0;
        c1 += (row[t + 256] != 0.0f) ? 1 : 0;
    }
    if (c0) atomicAdd(&ws[(WS_CNT >> 2) + t],       (uint32_t)c0);
    if (c1) atomicAdd(&ws[(WS_CNT >> 2) + t + 256], (uint32_t)c1);
}

// ---------------------------------------------------------------- prep B
// Counting-sort columns ascending by nnz; per-group padded trip counts
// (multiple of 16: both stream-halves get whole 8-entry chunks) + bases;
// pad entries (k16=0 -> reads neuron 0's spikes, w=+0.0f -> adds 0).
__global__ __launch_bounds__(512) void lsm_sort(uint32_t* __restrict__ ws)
{
    __shared__ int hist[N_NEU + 1];
    __shared__ int csort[N_NEU];
    __shared__ int gcw[8];

    int t = threadIdx.x;
    int creal = (int)ws[(WS_CNT >> 2) + t];
    for (int i = t; i < N_NEU + 1; i += 512) hist[i] = 0;
    __syncthreads();
    atomicAdd(&hist[creal], 1);
    __syncthreads();
    if (t == 0) {
        int acc = 0;
        for (int v = 0; v <= N_NEU; ++v) { int h = hist[v]; hist[v] = acc; acc += h; }
    }
    __syncthreads();
    int rank = atomicAdd(&hist[creal], 1);
    ws[(WS_PERM >> 2) + rank] = (uint32_t)t;
    ws[(WS_RANK >> 2) + t]    = (uint32_t)rank;
    csort[rank] = creal;
    __syncthreads();
    if (t < 8) {
        int cw = csort[t * 64 + 63];         // ascending -> group max is last
        cw = (cw + 15) & ~15;                // pad to multiple of 16
        gcw[t] = cw;
        ws[(WS_CNTW >> 2) + t] = (uint32_t)cw;
    }
    __syncthreads();
    if (t == 0) {
        int ai = 0, aw = 0;
        for (int g = 0; g < 8; ++g) {
            ws[(WS_IBASE >> 2) + g] = (uint32_t)ai;
            ws[(WS_WBASE >> 2) + g] = (uint32_t)aw;
            ai += gcw[g] * 64 * 2;           // bytes (u16 per entry)
            aw += gcw[g] * 64 * 4;           // bytes (f32 per entry)
        }
    }
    __syncthreads();
    // pad tail slots of this thread's column
    int wg = rank >> 6, ls = rank & 63;
    int cw = gcw[wg];
    uint32_t ib = ws[(WS_IBASE >> 2) + wg];
    uint32_t wb = ws[(WS_WBASE >> 2) + wg];
    char* base = (char*)ws;
    for (int j = creal; j < cw; ++j) {
        *(unsigned short*)(base + WS_IDX + ib + (j >> 3) * 1024 + ls * 16 + (j & 7) * 2) = 0;
        *(float*)(base + WS_WT + wb + (j >> 3) * 2048 + ls * 32 + (j & 7) * 4) = 0.0f;
    }
}

// ---------------------------------------------------------------- prep C
// One block per COLUMN, LDS-local cursor. Index stored PRE-SCALED (k*16 =
// byte offset of neuron k's half8 spike record) so main loop does no shift.
__global__ __launch_bounds__(64) void lsm_fill(
    const float* __restrict__ W, uint32_t* __restrict__ ws)
{
    int c    = blockIdx.x;
    int lane = threadIdx.x;
    char* base = (char*)ws;
    uint32_t rank = ws[(WS_RANK >> 2) + c];
    int wg = (int)(rank >> 6), ls = (int)(rank & 63);
    uint32_t ib = ws[(WS_IBASE >> 2) + wg];
    uint32_t wb = ws[(WS_WBASE >> 2) + wg];

    __shared__ int ctr;
    if (lane == 0) ctr = 0;
    __syncthreads();

    for (int k = lane; k < N_NEU; k += 64) {
        float wv = W[(size_t)k * N_NEU + c];
        if (wv != 0.0f) {
            int j = atomicAdd(&ctr, 1);      // order within column irrelevant
            *(unsigned short*)(base + WS_IDX + ib + (j >> 3) * 1024 + ls * 16 + (j & 7) * 2)
                = (unsigned short)(k << 4);
            *(float*)(base + WS_WT + wb + (j >> 3) * 2048 + ls * 32 + (j & 7) * 4) = wv;
        }
    }
}

// ---------------------------------------------------------------- main
// LDS map:
//   [0,8192)      spk : f16 [512 neurons][8 rows], 16 B/neuron (gather target;
//                 at offset 0 so gather addr == pre-scaled index)
//   [8192,24576)  recx: float[512 cols][8] (half-1 partial rec, 32 B/col)
//                 rl  : overlay at 8192, rates staging [8][256] (pre-loop)
__global__ __launch_bounds__(1024, 4) void lsm_main(
    const float* __restrict__ rates, const float* __restrict__ inW,
    const float* __restrict__ vin,   const float* __restrict__ cin,
    const int* __restrict__ nsteps_p,
    const uint32_t* __restrict__ ws, float* __restrict__ out)
{
    __shared__ __align__(16) unsigned char smem[24576];
    float* recx = (float*)(smem + 8192);
    float* rl   = (float*)(smem + 8192);         // overlay, pre-loop only

    int p    = threadIdx.x;
    int h    = p >> 9;          // stream half: 0 or 1
    int q    = p & 511;         // column slot
    int blk  = blockIdx.x;
    int r0   = blk * R_PB;
    int wg   = q >> 6;
    int lane = q & 63;
    int n    = (int)ws[(WS_PERM >> 2) + q];
    int cw   = (int)ws[(WS_CNTW >> 2) + wg];     // wave-uniform
    int nit  = cw >> 4;                          // 8-entry chunks per half
    const char* ip0 = (const char*)ws + WS_IDX + ws[(WS_IBASE >> 2) + wg]
                    + h * 1024 + lane * 16;
    const char* wp0 = (const char*)ws + WS_WT  + ws[(WS_WBASE >> 2) + wg]
                    + h * 2048 + lane * 32;

    // stage this block's 8 rate rows (2048 floats = 512 float4)
    if (p < 512)
        ((float4*)rl)[p] = ((const float4*)(rates + (size_t)r0 * D_IN))[p];
    __syncthreads();

    float c0v[R_PB], v0v[R_PB], ssum[R_PB], I[R_PB];
    if (h == 0) {
        // input current I[r] = rates[r,:] . inW[n,:] (constant across steps)
        #pragma unroll
        for (int r = 0; r < R_PB; ++r) I[r] = 0.f;
        const float4* wrow = (const float4*)(inW + (size_t)n * D_IN);
        for (int d4 = 0; d4 < D_IN / 4; ++d4) {
            float4 wv = wrow[d4];
            #pragma unroll
            for (int r = 0; r < R_PB; ++r) {
                const float* rr = rl + r * D_IN + d4 * 4;   // LDS broadcast
                I[r] += wv.x * rr[0] + wv.y * rr[1] + wv.z * rr[2] + wv.w * rr[3];
            }
        }
        // state load + initial f16 spikes
        half8 s0;
        #pragma unroll
        for (int r = 0; r < R_PB; ++r) {
            c0v[r] = cin[(size_t)(r0 + r) * N_NEU + n];
            v0v[r] = vin[(size_t)(r0 + r) * N_NEU + n];
            ssum[r] = 0.f;
            s0[r] = (c0v[r] > 0.f) ? (_Float16)1 : (_Float16)0;
        }
        __syncthreads();   // rl reads done before spk/recx region reuse
        *(half8*)(smem + (size_t)n * 16) = s0;
    } else {
        __syncthreads();   // matching barrier
    }

    const float AS   = (float)0.8187307530779818;   // exp(-1/5)
    const float OMAS = (float)(1.0 - 0.8187307530779818);
    const float AM   = (float)0.9512294245007140;   // exp(-1/20)
    const float OMAM = (float)(1.0 - 0.9512294245007140);

    int T = nsteps_p[0];
    __syncthreads();

    #pragma unroll 1
    for (int t = 0; t < T; ++t) {
        float rec[R_PB];
        #pragma unroll
        for (int r = 0; r < R_PB; ++r) rec[r] = 0.f;

        const char* ip = ip0;
        const char* wp = wp0;
        #pragma unroll 1
        for (int it = 0; it < nit; ++it) {
            uint4  X  = *(const uint4*)ip;           // 8 pre-scaled indices
            float4 Wa = ((const float4*)wp)[0];      // 8 exact f32 weights
            float4 Wb = ((const float4*)wp)[1];
            ip += 2048; wp += 4096;
            half8 s0 = *(const half8*)(smem + (X.x & 0xffffu));
            half8 s1 = *(const half8*)(smem + (X.x >> 16));
            half8 s2 = *(const half8*)(smem + (X.y & 0xffffu));
            half8 s3 = *(const half8*)(smem + (X.y >> 16));
            half8 s4 = *(const half8*)(smem + (X.z & 0xffffu));
            half8 s5 = *(const half8*)(smem + (X.z >> 16));
            half8 s6 = *(const half8*)(smem + (X.w & 0xffffu));
            half8 s7 = *(const half8*)(smem + (X.w >> 16));
            #pragma unroll
            for (int r = 0; r < R_PB; ++r) {
                float a = rec[r];
                a = fmaf(Wa.x, (float)s0[r], a);
                a = fmaf(Wa.y, (float)s1[r], a);
                a = fmaf(Wa.z, (float)s2[r], a);
                a = fmaf(Wa.w, (float)s3[r], a);
                a = fmaf(Wb.x, (float)s4[r], a);
                a = fmaf(Wb.y, (float)s5[r], a);
                a = fmaf(Wb.z, (float)s6[r], a);
                a = fmaf(Wb.w, (float)s7[r], a);
                rec[r] = a;
            }
        }

        if (h == 1) {
            float* rx = recx + (size_t)q * 8;
            *(float4*)rx       = make_float4(rec[0], rec[1], rec[2], rec[3]);
            *(float4*)(rx + 4) = make_float4(rec[4], rec[5], rec[6], rec[7]);
        }
        __syncthreads();   // half-1 partials visible; all spike reads done

        if (h == 0) {
            const float* rx = recx + (size_t)q * 8;
            half8 ns;
            #pragma unroll
            for (int r = 0; r < R_PB; ++r) {
                float rc = rec[r] + rx[r];
                c0v[r] = AS * c0v[r] + OMAS * (I[r] + rc);
                v0v[r] = AM * v0v[r] + OMAM * c0v[r];
                ssum[r] += (v0v[r] > 0.f) ? 1.f : 0.f;
                ns[r] = (c0v[r] > 0.f) ? (_Float16)1 : (_Float16)0;
            }
            *(half8*)(smem + (size_t)n * 16) = ns;
        }
        __syncthreads();   // new spikes visible
    }

    if (h == 0) {
        float invT = 1.0f / (float)T;
        size_t BN = (size_t)B_ROWS * N_NEU;
        #pragma unroll
        for (int r = 0; r < R_PB; ++r) {
            size_t off = (size_t)(r0 + r) * N_NEU + n;
            out[off]          = ssum[r] * invT;   // readout
            out[BN + off]     = v0v[r];           // final v
            out[2 * BN + off] = c0v[r];           // final c
        }
    }
}

// ---------------------------------------------------------------- launch
extern "C" void kernel_launch(void* const* d_in, const int* in_sizes, int n_in,
                              void* d_out, int out_size, void* d_ws, size_t ws_size,
                              hipStream_t stream)
{
    const float* rates = (const float*)d_in[0];
    const float* inW   = (const float*)d_in[1];
    const float* W     = (const float*)d_in[2];
    const float* vin   = (const float*)d_in[3];
    const float* cin   = (const float*)d_in[4];
    const int*   nst   = (const int*)d_in[5];
    uint32_t* ws = (uint32_t*)d_ws;
    float* out = (float*)d_out;
    (void)in_sizes; (void)n_in; (void)out_size; (void)ws_size;

    // zero CNT (harness poisons d_ws to 0xAA before every call)
    hipMemsetAsync((char*)d_ws + WS_CNT, 0, 2048, stream);

    lsm_count<<<128, 256, 0, stream>>>(W, ws);
    lsm_sort<<<1, 512, 0, stream>>>(ws);
    lsm_fill<<<N_NEU, 64, 0, stream>>>(W, ws);
    lsm_main<<<NBLK, 1024, 0, stream>>>(rates, inW, vin, cin, nst, ws, out);
}